// Round 15
// baseline (251.715 us; speedup 1.0000x reference)
//
#include <hip/hip_runtime.h>
#include <hip/hip_bf16.h>

// Dense FFN: out = relu(x @ w1 + b1) @ w2 + b2
// x  [8192,1024] f32, w1 [1024,4096] f32, b1 [4096] f32,
// w2 [4096,1024] f32, b2 [1024] f32, out [8192,1024] f32.
//
// R14 (resubmit after broker timeout) = R13 verified-best (250.5us) with ONE
// change: x-cast geometry.  Was 8192 blocks x 4KB each (tiny-block
// scheduling overhead); now 2048 blocks x 16 f32/thread (4x float4 reads,
// 2x 16B bf16x8 stores -- G11 grid sweet spot, doubled store width).
// Transposes and both GEMM bodies bit-identical to R13.

typedef __bf16 bf16;
typedef __bf16 bf16x4 __attribute__((ext_vector_type(4)));
typedef __bf16 bf16x8 __attribute__((ext_vector_type(8)));
typedef float  f32x4  __attribute__((ext_vector_type(4)));

#define BM 128
#define BN 128
#define BK 64

__device__ __forceinline__ void gload_lds16(const bf16* g, bf16* l) {
    __builtin_amdgcn_global_load_lds(
        (const __attribute__((address_space(1))) unsigned int*)g,
        (__attribute__((address_space(3))) unsigned int*)l,
        16, 0, 0);
}

// ---------------------------------------------------------------------------
// fused prep: [0,2048) cast x->bf16 (16 f32/thread); [2048,3072) w1
// transpose; [3072,4096) w2 transpose.  All block-uniform branches.
__device__ __forceinline__ void transpose_tile(
    const float* __restrict__ in, bf16* __restrict__ out,
    int K, int N, int k0, int n0, int t, bf16 (*tile)[72])
{
    const int lr = t >> 4;          // 0..15
    const int lc = (t & 15) << 2;   // 0,4,..60
#pragma unroll
    for (int p = 0; p < 4; ++p) {
        int k = p * 16 + lr;
        float4 v = *(const float4*)(in + (size_t)(k0 + k) * N + n0 + lc);
        tile[lc + 0][k] = (bf16)v.x;
        tile[lc + 1][k] = (bf16)v.y;
        tile[lc + 2][k] = (bf16)v.z;
        tile[lc + 3][k] = (bf16)v.w;
    }
    __syncthreads();

    const int wr = t >> 3;          // 0..31
    const int wc = (t & 7) << 3;    // 0,8,..56
#pragma unroll
    for (int p = 0; p < 2; ++p) {
        int n = p * 32 + wr;
        *(bf16x8*)(out + (size_t)(n0 + n) * K + k0 + wc) =
            *(const bf16x8*)&tile[n][wc];
    }
}

__global__ __launch_bounds__(256) void prep_fused(
    const float* __restrict__ x,  bf16* __restrict__ xb,
    const float* __restrict__ w1, bf16* __restrict__ w1t,
    const float* __restrict__ w2, bf16* __restrict__ w2t)
{
    __shared__ __align__(16) bf16 tile[64][72];
    const int bid = blockIdx.x;
    const int t   = threadIdx.x;

    if (bid < 2048) {
        // cast x: 8M f32 total; 2048 blk x 256 thr x 16 f32.
        const size_t e0 = ((size_t)bid * 256 + t) * 16;
        const float4* xin = (const float4*)(x + e0);
        float4 v0 = xin[0], v1 = xin[1], v2 = xin[2], v3 = xin[3];
        bf16x8 o0, o1;
        o0[0] = (bf16)v0.x; o0[1] = (bf16)v0.y; o0[2] = (bf16)v0.z; o0[3] = (bf16)v0.w;
        o0[4] = (bf16)v1.x; o0[5] = (bf16)v1.y; o0[6] = (bf16)v1.z; o0[7] = (bf16)v1.w;
        o1[0] = (bf16)v2.x; o1[1] = (bf16)v2.y; o1[2] = (bf16)v2.z; o1[3] = (bf16)v2.w;
        o1[4] = (bf16)v3.x; o1[5] = (bf16)v3.y; o1[6] = (bf16)v3.z; o1[7] = (bf16)v3.w;
        *(bf16x8*)(xb + e0)     = o0;
        *(bf16x8*)(xb + e0 + 8) = o1;
    } else if (bid < 3072) {
        int b = bid - 2048;   // w1 [1024][4096] -> w1t [4096][1024]
        transpose_tile(w1, w1t, 1024, 4096, (b >> 6) * 64, (b & 63) * 64, t, tile);
    } else {
        int b = bid - 3072;   // w2 [4096][1024] -> w2t [1024][4096]
        transpose_tile(w2, w2t, 4096, 1024, (b >> 4) * 64, (b & 15) * 64, t, tile);
    }
}

// ---------------------------------------------------------------------------
// GEMM1: C = relu(A @ Bt^T + bias), bf16 out.  Verified R2/R6 body:
// 128x128, BK=64, 256 thr, 16x16x32 MFMA, chunk-XOR swizzle (0 conflicts).
template <int FUSE_RELU_BF16>
__global__ __launch_bounds__(256, 3) void gemm_bt(
    const bf16* __restrict__ A, const bf16* __restrict__ Bt,
    const float* __restrict__ bias, void* __restrict__ Cout,
    int M, int N, int K)
{
    __shared__ __align__(16) bf16 As[BM * BK];
    __shared__ __align__(16) bf16 Bs[BN * BK];

    const int tid  = threadIdx.x;
    const int wave = tid >> 6;
    const int lane = tid & 63;

    const int l8  = lane >> 3;
    const int c8  = lane & 7;
    const int swc = (c8 ^ l8) << 3;
    const size_t K_ = (size_t)K;

    const bf16* gA[4]; const bf16* gB[4];
    bf16* lA[4]; bf16* lB[4];
#pragma unroll
    for (int g = 0; g < 4; ++g) {
        const int rr = wave * 32 + g * 8 + l8;
        gA[g] = A  + ((size_t)blockIdx.y * BM + rr) * K_ + swc;
        gB[g] = Bt + ((size_t)blockIdx.x * BN + rr) * K_ + swc;
        lA[g] = &As[(wave * 32 + g * 8) * BK] + lane * 8;
        lB[g] = &Bs[(wave * 32 + g * 8) * BK] + lane * 8;
    }

    const int wm   = (wave >> 1) << 6;
    const int wn   = (wave & 1) << 6;
    const int quad = lane >> 4;
    const int r    = lane & 15;
    const int r7   = lane & 7;

    f32x4 acc[4][4] = {};

    for (int k0 = 0; k0 < K; k0 += BK) {
        __syncthreads();
#pragma unroll
        for (int g = 0; g < 4; ++g) {
            gload_lds16(gA[g], lA[g]);
            gload_lds16(gB[g], lB[g]);
            gA[g] += BK; gB[g] += BK;
        }
        __syncthreads();

#pragma unroll
        for (int h = 0; h < 2; ++h) {
            const int ch = ((h * 4 + quad) ^ r7) << 3;
            bf16x8 af[4], bfr[4];
#pragma unroll
            for (int i = 0; i < 4; ++i)
                af[i] = *(const bf16x8*)&As[(wm + i * 16 + r) * BK + ch];
#pragma unroll
            for (int j = 0; j < 4; ++j)
                bfr[j] = *(const bf16x8*)&Bs[(wn + j * 16 + r) * BK + ch];
#pragma unroll
            for (int i = 0; i < 4; ++i)
#pragma unroll
                for (int j = 0; j < 4; ++j)
                    acc[i][j] = __builtin_amdgcn_mfma_f32_16x16x32_bf16(
                        af[i], bfr[j], acc[i][j], 0, 0, 0);
        }
    }

    const int m_base = blockIdx.y * BM + wm + quad * 4;
    const int n_base = blockIdx.x * BN + wn + r;
    float bv[4];
#pragma unroll
    for (int j = 0; j < 4; ++j) bv[j] = bias[n_base + j * 16];

    if (FUSE_RELU_BF16) {
        bf16* Cb = (bf16*)Cout;
#pragma unroll
        for (int i = 0; i < 4; ++i) {
#pragma unroll
            for (int p = 0; p < 4; ++p) {
                size_t row = (size_t)(m_base + i * 16 + p) * (size_t)N;
#pragma unroll
                for (int j = 0; j < 4; ++j) {
                    float v = acc[i][j][p] + bv[j];
                    v = v > 0.f ? v : 0.f;
                    Cb[row + n_base + j * 16] = (bf16)v;
                }
            }
        }
    } else {
        float* Cf = (float*)Cout;
#pragma unroll
        for (int i = 0; i < 4; ++i) {
#pragma unroll
            for (int p = 0; p < 4; ++p) {
                size_t row = (size_t)(m_base + i * 16 + p) * (size_t)N;
#pragma unroll
                for (int j = 0; j < 4; ++j) {
                    Cf[row + n_base + j * 16] = acc[i][j][p] + bv[j];
                }
            }
        }
    }
}

// ---------------------------------------------------------------------------
// GEMM2: out = A @ Bt^T + bias, f32 out.  Verified R9 body:
// 128x128 tile, BK=128, 256 thr, 32 K-iters, LDS 64 KiB (2 blocks/CU),
// 16-chunk XOR swizzle mask &15 (81.8 us, 0 conflicts).
__global__ __launch_bounds__(256, 2) void gemm_bt2_k128(
    const bf16* __restrict__ A, const bf16* __restrict__ Bt,
    const float* __restrict__ bias, float* __restrict__ Cf,
    int M, int N, int K)
{
    __shared__ __align__(16) bf16 As[128 * 128];   // 32 KiB
    __shared__ __align__(16) bf16 Bs[128 * 128];   // 32 KiB

    const int tid  = threadIdx.x;
    const int wave = tid >> 6;
    const int lane = tid & 63;

    const int sr   = tid >> 4;                     // 0..15
    const int swc  = ((tid & 15) ^ sr) << 3;       // elem offset of 16B chunk
    const size_t K_ = (size_t)K;

    const bf16* gA[8]; const bf16* gB[8];
    bf16* lA[8]; bf16* lB[8];
#pragma unroll
    for (int g = 0; g < 8; ++g) {
        const int rr = g * 16 + sr;
        gA[g] = A  + ((size_t)blockIdx.y * 128 + rr) * K_ + swc;
        gB[g] = Bt + ((size_t)blockIdx.x * 128 + rr) * K_ + swc;
        lA[g] = &As[(g * 16) * 128] + tid * 8;     // linear dest
        lB[g] = &Bs[(g * 16) * 128] + tid * 8;
    }

    const int wm   = (wave >> 1) << 6;
    const int wn   = (wave & 1) << 6;
    const int quad = lane >> 4;
    const int r    = lane & 15;

    f32x4 acc[4][4] = {};

    for (int k0 = 0; k0 < K; k0 += 128) {
        __syncthreads();
#pragma unroll
        for (int g = 0; g < 8; ++g) {
            gload_lds16(gA[g], lA[g]);
            gload_lds16(gB[g], lB[g]);
            gA[g] += 128; gB[g] += 128;
        }
        __syncthreads();

#pragma unroll
        for (int ks = 0; ks < 4; ++ks) {           // 4 k-sub-steps of 32
            bf16x8 af[4], bfr[4];
#pragma unroll
            for (int i = 0; i < 4; ++i) {
                const int row = wm + i * 16 + r;
                const int ch  = (((ks * 4 + quad) ^ (row & 15)) << 3);
                af[i] = *(const bf16x8*)&As[row * 128 + ch];
            }
#pragma unroll
            for (int j = 0; j < 4; ++j) {
                const int row = wn + j * 16 + r;
                const int ch  = (((ks * 4 + quad) ^ (row & 15)) << 3);
                bfr[j] = *(const bf16x8*)&Bs[row * 128 + ch];
            }
#pragma unroll
            for (int i = 0; i < 4; ++i)
#pragma unroll
                for (int j = 0; j < 4; ++j)
                    acc[i][j] = __builtin_amdgcn_mfma_f32_16x16x32_bf16(
                        af[i], bfr[j], acc[i][j], 0, 0, 0);
        }
    }

    const int m_base = blockIdx.y * 128 + wm + quad * 4;
    const int n_base = blockIdx.x * 128 + wn + r;
    float bv[4];
#pragma unroll
    for (int j = 0; j < 4; ++j) bv[j] = bias[n_base + j * 16];

#pragma unroll
    for (int i = 0; i < 4; ++i) {
#pragma unroll
        for (int p = 0; p < 4; ++p) {
            size_t row = (size_t)(m_base + i * 16 + p) * (size_t)N;
#pragma unroll
            for (int j = 0; j < 4; ++j) {
                Cf[row + n_base + j * 16] = acc[i][j][p] + bv[j];
            }
        }
    }
}

// ---------------------------------------------------------------------------
extern "C" void kernel_launch(void* const* d_in, const int* in_sizes, int n_in,
                              void* d_out, int out_size, void* d_ws, size_t ws_size,
                              hipStream_t stream)
{
    const float* x  = (const float*)d_in[0];  // [8192,1024]
    const float* w1 = (const float*)d_in[1];  // [1024,4096]
    const float* b1 = (const float*)d_in[2];  // [4096]
    const float* w2 = (const float*)d_in[3];  // [4096,1024]
    const float* b2 = (const float*)d_in[4];  // [1024]
    float* out = (float*)d_out;               // [8192,1024]

    const int M = 8192, D = 1024, W = 4096;

    char* ws = (char*)d_ws;
    bf16* xb  = (bf16*)(ws);                           // 16 MiB: [8192,1024]
    bf16* w1t = (bf16*)(ws + (size_t)(16 << 20));      //  8 MiB: [4096,1024]
    bf16* w2t = (bf16*)(ws + (size_t)(24 << 20));      //  8 MiB: [1024,4096]
    bf16* h   = (bf16*)(ws + (size_t)(32 << 20));      // 64 MiB: [8192,4096]

    // 1. fused prep: cast x (2048 blk) + transpose w1 + transpose w2
    prep_fused<<<4096, 256, 0, stream>>>(x, xb, w1, w1t, w2, w2t);

    // 2. h = relu(xb @ w1 + b1), bf16  [M][W]   128x128 tile, BK=64
    gemm_bt<1><<<dim3(W / BN, M / BM), 256, 0, stream>>>(
        xb, w1t, b1, (void*)h, M, W, D);

    // 3. out = h @ w2 + b2, f32  [M][D]         128x128 tile, BK=128
    gemm_bt2_k128<<<dim3(D / 128, M / 128), 256, 0, stream>>>(
        h, w2t, b2, out, M, D, W);
}